// Round 6
// baseline (252.039 us; speedup 1.0000x reference)
//
#include <hip/hip_runtime.h>
#include <math.h>

#define B_ 4
#define H_ 192
#define W_ 192
#define Q_ 160
#define E_ 96
#define M_ 96
#define HW_ (H_ * W_)          // 36864
#define NPIX_ (B_ * HW_)       // 147456
#define NDICE 1024             // 4096 waves; 9 pixel-positions per wave, all 4 batches each
#define NSMALL 962             // 2 + 384 + 576
#define NBUCKET 64
// ws layout (floats): [0]=class [1]=bce [2]=nll [3]=occ
//   [4   + k*4 + b] k<64 : dice numerator partials
//   [260 + k*4 + b] k<64 : sum_true partials
#define WS_NUM0 4
#define WS_TS0  260
#define WS_TOTAL 516

// ---- DPP wave-64 sum: result lands in lane 63 ----
template <int CTRL, int RMASK>
__device__ __forceinline__ float dpp_add_step(float x) {
    int v = __builtin_amdgcn_update_dpp(0, __float_as_int(x), CTRL, RMASK, 0xF, false);
    return x + __int_as_float(v);
}
__device__ __forceinline__ float wave_sum63(float x) {
    x = dpp_add_step<0x111, 0xF>(x);  // row_shr:1
    x = dpp_add_step<0x112, 0xF>(x);  // row_shr:2
    x = dpp_add_step<0x114, 0xF>(x);  // row_shr:4
    x = dpp_add_step<0x118, 0xF>(x);  // row_shr:8
    x = dpp_add_step<0x142, 0xA>(x);  // row_bcast:15 -> rows 1,3
    x = dpp_add_step<0x143, 0xC>(x);  // row_bcast:31 -> rows 2,3
    return x;                          // lane 63 = full sum
}

__device__ __forceinline__ float waveSumAll(float v) {
    for (int m = 32; m > 0; m >>= 1) v += __shfl_xor(v, m, 64);
    return v;
}

__device__ __forceinline__ float softplusf(float x) {
    return fmaxf(x, 0.f) + log1pf(__expf(-fabsf(x)));
}

// load all 4 batches' gathered values for pixel position P (16 scattered loads,
// no interdependence -> compiler issues them back-to-back)
#define LOAD_POS(P, P0, T0, P1, T1) do {                                   \
    const size_t _p = (size_t)(P);                                         \
    const float* _r0 = pb0 + _p * Q_; const float* _r1 = pb1 + _p * Q_;    \
    const float* _r2 = pb2 + _p * Q_; const float* _r3 = pb3 + _p * Q_;    \
    const float* _s0 = tb0 + _p * E_; const float* _s1 = tb1 + _p * E_;    \
    const float* _s2 = tb2 + _p * E_; const float* _s3 = tb3 + _p * E_;    \
    P0.x = _r0[mqa0]; P0.y = _r1[mqa1]; P0.z = _r2[mqa2]; P0.w = _r3[mqa3];\
    T0.x = _s0[mea0]; T0.y = _s1[mea1]; T0.z = _s2[mea2]; T0.w = _s3[mea3];\
    if (hi) {                                                              \
        P1.x = _r0[mqb0]; P1.y = _r1[mqb1]; P1.z = _r2[mqb2]; P1.w = _r3[mqb3]; \
        T1.x = _s0[meb0]; T1.y = _s1[meb1]; T1.z = _s2[meb2]; T1.w = _s3[meb3]; \
    } else {                                                               \
        P1.x = P1.y = P1.z = P1.w = 0.f;                                   \
        T1.x = T1.y = T1.z = T1.w = 0.f;                                   \
    }                                                                      \
} while (0)

#define DICE_ONE(p0c, t0c, p1c, t1c, anref, atref) do {                    \
    float _e1 = hi ? __expf(p1c) : 0.f;                                    \
    float _e0 = __expf(p0c);                                               \
    float _s  = wave_sum63(_e0 + _e1);                                     \
    float _se = wave_sum63(fmaf(t0c, _e0, t1c * _e1));                     \
    anref += __fdividef(_se, _s);                                          \
    atref += t0c + t1c;                                                    \
} while (0)

// ---------------------------------------------------------------------------
// Fused kernel. Block regions:
//   [0, 1024)        dice (numerator + sum_true), direct gathers, no barriers
//   [1024, 1986)     small: +0 class, +1 nll, +2..385 bce 7x7, +386..961 occ CE
// ---------------------------------------------------------------------------
__global__ __launch_bounds__(256) void fused_kernel(
    const float* __restrict__ logit,    // [640]
    const float* __restrict__ trueseg,  // [B,H,W,E]
    const float* __restrict__ binlog,   // [B,H,W,Q]
    const float* __restrict__ por,      // [B,H,W,Q]
    const float* __restrict__ inc,      // [B,E,2]
    const float* __restrict__ pos,      // [B,Q,2]
    const float* __restrict__ chol,     // [B,Q,2,2]
    const float* __restrict__ occlog,   // [B,H,W,4]
    const int* __restrict__ occtrue,    // [B,H,W]
    const int* __restrict__ mqall,      // [B,M]
    const int* __restrict__ meall,      // [B,M]
    float* __restrict__ ws)
{
    __shared__ float red[256];
    __shared__ float lab[B_ * Q_];
    __shared__ float sA[4][B_], sT[4][B_];
    const int tid  = threadIdx.x;
    const int lane = tid & 63;
    const int wid  = tid >> 6;
    const int blk  = blockIdx.x;

    if (blk < NDICE) {
        // ================= dice: numerator + true-sum, all 4 batches =========
        const int wave = blk * 4 + wid;            // 0..4095
        const bool hi = lane < 32;
        // hoist gather indices for all batches into registers
        const int mqa0 = mqall[0 * M_ + lane], mqa1 = mqall[1 * M_ + lane],
                  mqa2 = mqall[2 * M_ + lane], mqa3 = mqall[3 * M_ + lane];
        const int mea0 = meall[0 * M_ + lane], mea1 = meall[1 * M_ + lane],
                  mea2 = meall[2 * M_ + lane], mea3 = meall[3 * M_ + lane];
        int mqb0 = 0, mqb1 = 0, mqb2 = 0, mqb3 = 0;
        int meb0 = 0, meb1 = 0, meb2 = 0, meb3 = 0;
        if (hi) {
            mqb0 = mqall[0 * M_ + 64 + lane]; mqb1 = mqall[1 * M_ + 64 + lane];
            mqb2 = mqall[2 * M_ + 64 + lane]; mqb3 = mqall[3 * M_ + 64 + lane];
            meb0 = meall[0 * M_ + 64 + lane]; meb1 = meall[1 * M_ + 64 + lane];
            meb2 = meall[2 * M_ + 64 + lane]; meb3 = meall[3 * M_ + 64 + lane];
        }
        const float* pb0 = por;
        const float* pb1 = por + (size_t)1 * HW_ * Q_;
        const float* pb2 = por + (size_t)2 * HW_ * Q_;
        const float* pb3 = por + (size_t)3 * HW_ * Q_;
        const float* tb0 = trueseg;
        const float* tb1 = trueseg + (size_t)1 * HW_ * E_;
        const float* tb2 = trueseg + (size_t)2 * HW_ * E_;
        const float* tb3 = trueseg + (size_t)3 * HW_ * E_;

        float4 an = {0.f, 0.f, 0.f, 0.f};   // numerator per batch (valid lane 63)
        float4 at = {0.f, 0.f, 0.f, 0.f};   // true-sum per batch (per-lane partial)

        float4 cP0, cT0, cP1, cT1, nP0, nT0, nP1, nT1;
        LOAD_POS(wave, cP0, cT0, cP1, cT1);
        #pragma unroll
        for (int it = 0; it < 9; ++it) {
            if (it < 8) LOAD_POS(wave + (it + 1) * 4096, nP0, nT0, nP1, nT1);
            DICE_ONE(cP0.x, cT0.x, cP1.x, cT1.x, an.x, at.x);
            DICE_ONE(cP0.y, cT0.y, cP1.y, cT1.y, an.y, at.y);
            DICE_ONE(cP0.z, cT0.z, cP1.z, cT1.z, an.z, at.z);
            DICE_ONE(cP0.w, cT0.w, cP1.w, cT1.w, an.w, at.w);
            cP0 = nP0; cT0 = nT0; cP1 = nP1; cT1 = nT1;
        }
        at.x = wave_sum63(at.x); at.y = wave_sum63(at.y);
        at.z = wave_sum63(at.z); at.w = wave_sum63(at.w);
        if (lane == 63) {
            sA[wid][0] = an.x; sA[wid][1] = an.y; sA[wid][2] = an.z; sA[wid][3] = an.w;
            sT[wid][0] = at.x; sT[wid][1] = at.y; sT[wid][2] = at.z; sT[wid][3] = at.w;
        }
        __syncthreads();
        if (tid < B_) {
            float num = sA[0][tid] + sA[1][tid] + sA[2][tid] + sA[3][tid];
            float ts  = sT[0][tid] + sT[1][tid] + sT[2][tid] + sT[3][tid];
            int bucket = blk & (NBUCKET - 1);
            atomicAdd(&ws[WS_NUM0 + bucket * 4 + tid], 2.f * num);
            atomicAdd(&ws[WS_TS0  + bucket * 4 + tid], ts);
        }
    } else {
        const int s = blk - NDICE;
        float acc = 0.f;
        if (s == 0) {
            // ---- class loss ----
            for (int i = tid; i < B_ * Q_; i += 256) lab[i] = 0.f;
            __syncthreads();
            for (int i = tid; i < B_ * M_; i += 256) {
                int b = i / M_;
                lab[b * Q_ + mqall[i]] = 1.f;
            }
            __syncthreads();
            for (int i = tid; i < B_ * Q_; i += 256) {
                float x = logit[i];
                float z = lab[i];
                float w = z > 0.f ? 1.f : 0.1f;
                acc += w * (softplusf(x) - x * z);
            }
            red[tid] = acc; __syncthreads();
            for (int st = 128; st > 0; st >>= 1) { if (tid < st) red[tid] += red[tid + st]; __syncthreads(); }
            if (tid == 0) ws[0] = red[0];
        } else if (s == 1) {
            // ---- distance NLL ----
            for (int i = tid; i < B_ * M_; i += 256) {
                int b = i / M_;
                int qi = mqall[i];
                int ei = meall[i];
                float px = inc[(b * E_ + ei) * 2 + 0];
                float py = inc[(b * E_ + ei) * 2 + 1];
                float cx = pos[(b * Q_ + qi) * 2 + 0];
                float cy = pos[(b * Q_ + qi) * 2 + 1];
                const float* ch = chol + (size_t)(b * Q_ + qi) * 4;
                float l00 = ch[0], l10 = ch[2], l11 = ch[3];
                float d0 = px - cx, d1 = py - cy;
                float z0 = d0 / l00;
                float z1 = (d1 - l10 * z0) / l11;
                float nll = 0.5f * (z0 * z0 + z1 * z1) + 1.837877066409345f
                            + logf(l00) + logf(l11);
                if (isinf(nll)) nll = 1e7f;
                acc += nll;
            }
            red[tid] = acc; __syncthreads();
            for (int st = 128; st > 0; st >>= 1) { if (tid < st) red[tid] += red[tid + st]; __syncthreads(); }
            if (tid == 0) ws[2] = red[0];
        } else if (s < 386) {
            // ---- 7x7 window BCE, one block per (b, m) ----
            int idx = s - 2;
            int b = idx / M_;
            int ei = meall[idx];
            int qi = mqall[idx];
            float px = inc[(b * E_ + ei) * 2 + 0];
            float py = inc[(b * E_ + ei) * 2 + 1];
            int r0 = (int)floorf(px) - 3;
            int c0 = (int)floorf(py) - 3;
            if (tid < 49) {
                int rr = r0 + tid / 7;
                int cc = c0 + tid % 7;
                size_t pix = ((size_t)b * H_ + rr) * W_ + cc;
                float tv = trueseg[pix * E_ + ei];
                float lg = binlog[pix * Q_ + qi];
                acc = softplusf(lg) - lg * tv;
            }
            red[tid] = acc; __syncthreads();
            for (int st = 128; st > 0; st >>= 1) { if (tid < st) red[tid] += red[tid + st]; __syncthreads(); }
            if (tid == 0) atomicAdd(&ws[1], red[0]);
        } else {
            // ---- occupancy cross-entropy, 256 pixels per block ----
            int p = (s - 386) * 256 + tid;
            if (p < NPIX_) {
                float4 v = *(const float4*)(occlog + (size_t)p * 4);
                int lb = occtrue[p];
                float m = fmaxf(fmaxf(v.x, v.y), fmaxf(v.z, v.w));
                float lse = m + __logf(__expf(v.x - m) + __expf(v.y - m) +
                                       __expf(v.z - m) + __expf(v.w - m));
                float xs = lb == 0 ? v.x : (lb == 1 ? v.y : (lb == 2 ? v.z : v.w));
                acc = lse - xs;
            }
            red[tid] = acc; __syncthreads();
            for (int st = 128; st > 0; st >>= 1) { if (tid < st) red[tid] += red[tid + st]; __syncthreads(); }
            if (tid == 0) atomicAdd(&ws[3], red[0]);
        }
    }
}

// ---------------------------------------------------------------------------
// Final combine: one wave. Lane k owns bucket k.
// ---------------------------------------------------------------------------
__global__ __launch_bounds__(64) void final_kernel(const float* __restrict__ ws,
                                                   float* __restrict__ out)
{
    const int lane = threadIdx.x;
    float n[B_], t[B_];
    for (int b = 0; b < B_; ++b) {
        n[b] = waveSumAll(ws[WS_NUM0 + lane * 4 + b]);
        t[b] = waveSumAll(ws[WS_TS0  + lane * 4 + b]);
    }
    if (lane == 0) {
        float class_l = ws[0] * (1.f / (B_ * Q_));
        float bce_l   = ws[1] * (1.f / (B_ * M_ * 49));
        float nll_l   = ws[2] * (1.f / (B_ * M_));
        float occ_l   = ws[3] * (1.f / NPIX_);
        float dice = 0.f;
        for (int b = 0; b < B_; ++b)
            dice += 1.f - (n[b] + 1.f) / (t[b] + (float)HW_ + 1.f);
        dice *= (1.f / B_);
        out[0] = class_l + bce_l + nll_l + occ_l + dice;
    }
}

extern "C" void kernel_launch(void* const* d_in, const int* in_sizes, int n_in,
                              void* d_out, int out_size, void* d_ws, size_t ws_size,
                              hipStream_t stream) {
    const float* logit   = (const float*)d_in[0];
    const float* trueseg = (const float*)d_in[1];
    const float* binlog  = (const float*)d_in[2];
    const float* por     = (const float*)d_in[3];
    const float* inc     = (const float*)d_in[4];
    const float* pos     = (const float*)d_in[5];
    const float* chol    = (const float*)d_in[6];
    const float* occlog  = (const float*)d_in[7];
    const int*   occtrue = (const int*)d_in[8];
    const int*   mq      = (const int*)d_in[9];
    const int*   me      = (const int*)d_in[10];
    float* out = (float*)d_out;
    float* ws  = (float*)d_ws;

    (void)hipMemsetAsync(d_ws, 0, WS_TOTAL * sizeof(float), stream);

    hipLaunchKernelGGL(fused_kernel, dim3(NDICE + NSMALL), dim3(256), 0, stream,
                       logit, trueseg, binlog, por, inc, pos, chol, occlog, occtrue,
                       mq, me, ws);
    hipLaunchKernelGGL(final_kernel, dim3(1), dim3(64), 0, stream, ws, out);
}